// Round 3
// baseline (10890.688 us; speedup 1.0000x reference)
//
#include <hip/hip_runtime.h>
#include <hip/hip_bf16.h>
#include <math.h>

#define T_STEPS 256
#define BATCH   256
#define FDIM    128
#define HDIM    384
#define KWIN    10
#define GDIM    1542
#define SDIM    64
#define NGC     1536   // packed gate cols: col' = ugrp*64 + gate*16 + (u%16)
#define KA      512    // GEMM K = HDIM + FDIM (bias rows folded)
#define BH      (BATCH*HDIM)   // 98304
#define NBLK    192    // 8 rowgroups x 24 colgroups
#define NTHR    320    // 5 waves

typedef __bf16 bf16x8 __attribute__((ext_vector_type(8)));
typedef float  f32x4  __attribute__((ext_vector_type(4)));

__device__ __forceinline__ float sigmoidf_(float x){ return 1.f/(1.f+__expf(-x)); }

// ---------------- init: zero h ping buffer + barrier words ----------------
__global__ void init_state(__bf16* __restrict__ hbA, unsigned* __restrict__ bar){
    int i = blockIdx.x*256 + threadIdx.x;   // BH threads
    hbA[i] = (__bf16)0.f;
    if (i < 2) bar[i] = 0u;
}

// ---------------- cast x (T*B*F fp32) -> bf16 ----------------
__global__ void cast_x(const float* __restrict__ x, __bf16* __restrict__ xb, int n){
    int i = (blockIdx.x*256 + threadIdx.x)*4;
    if (i < n){
        float4 v = *(const float4*)(x+i);
        xb[i+0]=(__bf16)v.x; xb[i+1]=(__bf16)v.y; xb[i+2]=(__bf16)v.z; xb[i+3]=(__bf16)v.w;
    }
}

// ---------------- pack gate weights: Bg[k8][col'][8], col' = ugrp*64+gate*16+um ----------------
__global__ void pack_w_gate(const float* __restrict__ Wk, const float* __restrict__ bk,
                            const float* __restrict__ Wr, const float* __restrict__ br,
                            __bf16* __restrict__ Bg, float* __restrict__ cg){
    int gid = blockIdx.x*256 + threadIdx.x;    // 64*1536 = 98304
    int k8  = gid / NGC;
    int col = gid - k8*NGC;
    int ugrp = col >> 6;
    int rem  = col & 63;
    int gate = rem >> 4;
    int um   = rem & 15;
    int u    = ugrp*16 + um;
    int g    = 6 + gate*HDIM + u;
    bf16x8 out;
    #pragma unroll
    for (int j=0;j<8;++j){
        int k = k8*8 + j;
        float v = (k < HDIM) ? Wr[k*GDIM + g] : Wk[(k-HDIM)*GDIM + g];
        out[j] = (__bf16)v;
    }
    *(bf16x8*)(Bg + (size_t)gid*8) = out;
    if (k8 == 0)
        cg[col] = Wk[FDIM*GDIM + g] + bk[g] + Wr[HDIM*GDIM + g] + br[g];
}

// ---------------- pack head weights: Bh[k8][16][8] (cols 0..5 valid) ----------------
__global__ void pack_w_head(const float* __restrict__ Wk, const float* __restrict__ bk,
                            const float* __restrict__ Wr, const float* __restrict__ br,
                            __bf16* __restrict__ Bh, float* __restrict__ ch){
    int gid = blockIdx.x*256 + threadIdx.x;    // 64*16 = 1024
    int k8  = gid >> 4;
    int colh = gid & 15;
    bf16x8 out;
    #pragma unroll
    for (int j=0;j<8;++j){
        int k = k8*8 + j;
        float v = 0.f;
        if (colh < 6) v = (k < HDIM) ? Wr[k*GDIM + colh] : Wk[(k-HDIM)*GDIM + colh];
        out[j] = (__bf16)v;
    }
    *(bf16x8*)(Bh + (size_t)gid*8) = out;
    if (k8 == 0)
        ch[colh] = (colh < 6) ? (Wk[FDIM*GDIM + colh] + bk[colh] + Wr[HDIM*GDIM + colh] + br[colh]) : 0.f;
}

// ---------------- persistent recurrence kernel ----------------
// 192 blocks x 320 threads. block = (rowgroup rg: 32 rows) x (colgroup cgp: 16 units)
// waves 0-3: gate `wave` for the 16 units, full K in registers (64 VGPR)
// wave 4  : head (6 cols), full K in registers
__global__ void __launch_bounds__(NTHR, 1) persist(
    const __bf16* __restrict__ xb, const __bf16* __restrict__ Bg, const __bf16* __restrict__ Bh,
    const float* __restrict__ cg, const float* __restrict__ ch,
    __bf16* __restrict__ hbA, __bf16* __restrict__ hbB,
    float* __restrict__ bufh, float* __restrict__ bufd, float* __restrict__ hf,
    unsigned* __restrict__ bar)
{
    __shared__ __bf16 Alds[32*512];        // 32 KB, XOR-swizzled rows
    __shared__ float  accG[4][32][17];     // gate pre-acts (+bias), padded stride
    __shared__ float  headL[32][8];        // raw head pre-acts (+bias)

    const int tid  = threadIdx.x;
    const int wave = tid >> 6, lane = tid & 63;
    const int rg   = blockIdx.x / 24, cgp = blockIdx.x % 24;
    const int row0 = rg * 32;
    const int ccol = lane & 15, krow = lane >> 4;

    // ---- load weights into registers (persist across all 256 steps) ----
    bf16x8 wfrag[16];
    float biasv;
    if (wave < 4){
        int colb = cgp*64 + wave*16;
        #pragma unroll
        for (int ks=0; ks<16; ++ks)
            wfrag[ks] = *(const bf16x8*)(Bg + (((size_t)ks*4 + krow)*NGC + colb + ccol)*8);
        biasv = cg[colb + ccol];
    } else {
        #pragma unroll
        for (int ks=0; ks<16; ++ks)
            wfrag[ks] = *(const bf16x8*)(Bh + (((size_t)ks*4 + krow)*16 + ccol)*8);
        biasv = ch[ccol];
    }

    float creg0 = 0.f, creg1 = 0.f;        // register-resident cell state (2 rows/thread)
    unsigned ep = 0;

    for (int t=0; t<T_STEPS; ++t){
        const __bf16* hbp = (t & 1) ? hbB : hbA;
        __bf16*       hbn = (t & 1) ? hbA : hbB;

        // ---- stage A = [h | x_t] rows row0..row0+31 into LDS (swizzled) ----
        for (int q = tid; q < 2048; q += NTHR){
            int r  = q >> 6;
            int kk = q & 63;
            int grow = row0 + r;
            bf16x8 v;
            if (kk < 48) v = *(const bf16x8*)(hbp + (size_t)grow*HDIM + kk*8);
            else         v = *(const bf16x8*)(xb + ((size_t)t*BATCH + grow)*FDIM + (kk-48)*8);
            int ei = (r*512 + kk*8) ^ ((r & 7) << 3);
            *(bf16x8*)(Alds + ei) = v;
        }
        __syncthreads();

        // ---- MFMA: 2 M-tiles x 16 k-steps, B from registers ----
        f32x4 acc0 = {}, acc1 = {};
        #pragma unroll
        for (int ks=0; ks<16; ++ks){
            int kbase = ks*32 + krow*8;
            int e0 = ( ccol      *512 + kbase) ^ ((ccol & 7) << 3);
            int e1 = ((ccol + 16)*512 + kbase) ^ ((ccol & 7) << 3);
            bf16x8 a0 = *(const bf16x8*)(Alds + e0);
            bf16x8 a1 = *(const bf16x8*)(Alds + e1);
            acc0 = __builtin_amdgcn_mfma_f32_16x16x32_bf16(a0, wfrag[ks], acc0, 0,0,0);
            acc1 = __builtin_amdgcn_mfma_f32_16x16x32_bf16(a1, wfrag[ks], acc1, 0,0,0);
        }

        // ---- scatter pre-activations to LDS (C/D: col=lane&15, row=krow*4+i) ----
        if (wave < 4){
            #pragma unroll
            for (int i=0;i<4;++i){
                accG[wave][krow*4+i     ][ccol] = acc0[i] + biasv;
                accG[wave][krow*4+i + 16][ccol] = acc1[i] + biasv;
            }
        } else if (ccol < 6){
            #pragma unroll
            for (int i=0;i<4;++i){
                headL[krow*4+i     ][ccol] = acc0[i] + biasv;
                headL[krow*4+i + 16][ccol] = acc1[i] + biasv;
            }
        }
        __syncthreads();

        // ---- gates + state update: 256 threads x 2 rows, c in registers ----
        if (tid < 256){
            int ul = tid & 15;
            int rb = (tid >> 4) * 2;
            int slot = t - (T_STEPS - KWIN);
            #pragma unroll
            for (int j=0; j<2; ++j){
                int r = rb + j;
                int grow = row0 + r;
                float a0 = headL[r][0], a1 = headL[r][1], a2 = headL[r][2];
                float b0 = headL[r][3], b1 = headL[r][4], b2 = headL[r][5];
                float m1v = fmaxf(fmaxf(a0,a1),a2);
                float e0=__expf(a0-m1v), e1=__expf(a1-m1v), e2=__expf(a2-m1v);
                float inv = 1.f/(e0+e1+e2);
                float fm0 = e0*inv, fm1 = fm0 + e1*inv, fm2 = fm1 + e2*inv;
                float m2v = fmaxf(fmaxf(b0,b1),b2);
                float f0=__expf(b0-m2v), f1=__expf(b1-m2v), f2=__expf(b2-m2v);
                float inv2 = 1.f/(f0+f1+f2);
                float im2 = f2*inv2, im1 = im2 + f1*inv2, im0 = im1 + f0*inv2;
                int u = cgp*16 + ul;
                int l = u >> 7;
                float fml = (l==0)?fm0:((l==1)?fm1:fm2);
                float iml = (l==0)?im0:((l==1)?im1:im2);
                float fg = sigmoidf_(accG[0][r][ul]);
                float ig = sigmoidf_(accG[1][r][ul]);
                float og = sigmoidf_(accG[2][r][ul]);
                float ci = tanhf   (accG[3][r][ul]);
                float cold = j ? creg1 : creg0;
                float ov = fml*iml;
                float cn = ov*(fg*cold + ig*ci) + (fml-ov)*cold + (iml-ov)*ci;
                float h  = og * tanhf(cn);
                if (j) creg1 = cn; else creg0 = cn;
                size_t idx = (size_t)grow*HDIM + u;
                hbn[idx] = (__bf16)h;
                if (slot >= 0) bufh[(size_t)slot*BH + idx] = h;
                if (t == T_STEPS-1) hf[idx] = h;
                if (slot >= 0 && cgp == 0 && ul == 0)
                    bufd[slot*BATCH + grow] = 1.f - (fm0+fm1+fm2)*(1.f/3.f);
            }
        }

        // ---- device-scope barrier (one per step; h is ping-ponged) ----
        __threadfence();
        __syncthreads();
        ++ep;
        if (tid == 0){
            unsigned prev = __hip_atomic_fetch_add(bar, 1u, __ATOMIC_ACQ_REL, __HIP_MEMORY_SCOPE_AGENT);
            if (prev == NBLK-1){
                __hip_atomic_store(bar, 0u, __ATOMIC_RELAXED, __HIP_MEMORY_SCOPE_AGENT);
                __hip_atomic_fetch_add(bar+1, 1u, __ATOMIC_RELEASE, __HIP_MEMORY_SCOPE_AGENT);
            } else {
                while (__hip_atomic_load(bar+1, __ATOMIC_RELAXED, __HIP_MEMORY_SCOPE_AGENT) < ep)
                    __builtin_amdgcn_s_sleep(1);
            }
        }
        __syncthreads();
        __threadfence();
    }
}

// ---------------- finals ----------------
__global__ void final_locdis(const float* __restrict__ bufd, float* __restrict__ locdis){
    int b = threadIdx.x;   // 256
    float d[KWIN]; float cum = 0.f;
    #pragma unroll
    for (int k=0;k<KWIN;++k){ cum += bufd[k*BATCH + b]; d[k] = cum; }
    float m = d[0];
    #pragma unroll
    for (int k=1;k<KWIN;++k) m = fmaxf(m, d[k]);
    float s = 0.f;
    #pragma unroll
    for (int k=0;k<KWIN;++k){ d[k] = __expf(d[k]-m); s += d[k]; }
    float invs = 1.f/s;
    #pragma unroll
    for (int k=0;k<KWIN;++k) locdis[b*KWIN + k] = d[k]*invs;
}

__global__ void final_lh(const float* __restrict__ bufh, const float* __restrict__ locdis,
                         float* __restrict__ lh, float* __restrict__ mh){
    int gid = blockIdx.x*256 + threadIdx.x;    // BH
    int b = gid / HDIM;
    int i = gid - b*HDIM;
    float s = 0.f;
    #pragma unroll
    for (int k=0;k<KWIN;++k){
        float v = bufh[(size_t)k*BH + gid] * locdis[b*KWIN + k];
        lh[(size_t)b*(HDIM*KWIN) + i*KWIN + k] = v;
        s += v;
    }
    mh[gid] = s * (1.f/KWIN);
}

__global__ __launch_bounds__(256) void final_conv(const float* __restrict__ lh, const float* __restrict__ Wc,
                                                  const float* __restrict__ bc, float* __restrict__ cvout){
    __shared__ float As[32*257];
    __shared__ float Bs[32*257];
    int tid = threadIdx.x;
    int bb = blockIdx.x / 12, ob = blockIdx.x % 12;   // 8 x 12 = 96 blocks
    int tx = tid & 15, ty = tid >> 4;
    float acc00=0.f, acc01=0.f, acc10=0.f, acc11=0.f;
    const int KD = HDIM*KWIN;   // 3840 = 15 * 256
    for (int ch=0; ch<15; ++ch){
        #pragma unroll
        for (int p=0;p<8;++p){
            int q   = tid + p*256;
            int row = q >> 6;
            int c4  = q & 63;
            float4 va = *(const float4*)(lh + (size_t)(bb*32+row)*KD + ch*256 + c4*4);
            float4 vb = *(const float4*)(Wc + (size_t)(ob*32+row)*KD + ch*256 + c4*4);
            int o = row*257 + c4*4;
            As[o+0]=va.x; As[o+1]=va.y; As[o+2]=va.z; As[o+3]=va.w;
            Bs[o+0]=vb.x; Bs[o+1]=vb.y; Bs[o+2]=vb.z; Bs[o+3]=vb.w;
        }
        __syncthreads();
        for (int kk=0; kk<256; ++kk){
            float x0 = As[ty*257+kk],      x1 = As[(ty+16)*257+kk];
            float w0 = Bs[tx*257+kk],      w1 = Bs[(tx+16)*257+kk];
            acc00 += x0*w0; acc01 += x0*w1; acc10 += x1*w0; acc11 += x1*w1;
        }
        __syncthreads();
    }
    int r0 = bb*32+ty, r1 = r0+16, o0 = ob*32+tx, o1 = o0+16;
    cvout[(size_t)r0*HDIM + o0] = acc00 + bc[o0];
    cvout[(size_t)r0*HDIM + o1] = acc01 + bc[o1];
    cvout[(size_t)r1*HDIM + o0] = acc10 + bc[o0];
    cvout[(size_t)r1*HDIM + o1] = acc11 + bc[o1];
}

__global__ void final_th1(const float* __restrict__ mh, const float* __restrict__ Ws,
                          const float* __restrict__ bs, float* __restrict__ th1){
    int gid = blockIdx.x*256 + threadIdx.x;   // 256*64
    int b = gid >> 6, s = gid & 63;
    float acc = bs[s];
    const float* mr = mh + (size_t)b*HDIM;
    for (int i=0;i<HDIM;++i) acc += mr[i] * Ws[i*SDIM + s];
    th1[gid] = fmaxf(acc, 0.f);
}

__global__ void final_theme(const float* __restrict__ th1, const float* __restrict__ Wrs,
                            const float* __restrict__ brs, float* __restrict__ theme){
    int gid = blockIdx.x*256 + threadIdx.x;   // BH
    int b = gid / HDIM, o = gid - b*HDIM;
    float acc = brs[o];
    const float* tr = th1 + b*SDIM;
    for (int j=0;j<SDIM;++j) acc += tr[j] * Wrs[j*HDIM + o];
    theme[gid] = sigmoidf_(acc);
}

__global__ void final_out(const float* __restrict__ theme, const float* __restrict__ cvout,
                          const float* __restrict__ hf, const float* __restrict__ Wo,
                          const float* __restrict__ bo, float* __restrict__ out){
    int b = blockIdx.x, lane = threadIdx.x;   // 256 blocks x 64 threads
    float s = 0.f;
    for (int u=lane; u<HDIM; u+=64){
        float r = theme[(size_t)b*HDIM+u]*cvout[(size_t)b*HDIM+u] + hf[(size_t)b*HDIM+u];
        s += r * Wo[u];
    }
    #pragma unroll
    for (int off=32; off; off>>=1) s += __shfl_down(s, off);
    if (lane == 0) out[b] = sigmoidf_(s + bo[0]);
}

extern "C" void kernel_launch(void* const* d_in, const int* in_sizes, int n_in,
                              void* d_out, int out_size, void* d_ws, size_t ws_size,
                              hipStream_t stream){
    const float* x   = (const float*)d_in[0];
    const float* Wk  = (const float*)d_in[1];
    const float* bk  = (const float*)d_in[2];
    const float* Wr  = (const float*)d_in[3];
    const float* br  = (const float*)d_in[4];
    const float* Ws  = (const float*)d_in[5];
    const float* bs  = (const float*)d_in[6];
    const float* Wrs = (const float*)d_in[7];
    const float* brs = (const float*)d_in[8];
    const float* Wc  = (const float*)d_in[9];
    const float* bc  = (const float*)d_in[10];
    const float* Wo  = (const float*)d_in[11];
    const float* bo  = (const float*)d_in[12];
    float* out = (float*)d_out;

    char* w = (char*)d_ws;
    auto alloc = [&](size_t bytes)->char*{ char* p = w; w += (bytes + 255) & ~(size_t)255; return p; };
    __bf16* xb    = (__bf16*)alloc((size_t)T_STEPS*BATCH*FDIM*2);   // 16.8 MB
    __bf16* Bg    = (__bf16*)alloc((size_t)(KA/8)*NGC*8*2);         // 1.57 MB
    __bf16* Bh    = (__bf16*)alloc((size_t)(KA/8)*16*8*2);          // 16 KB
    float* cg     = (float*) alloc(NGC*4);
    float* ch     = (float*) alloc(16*4);
    __bf16* hbA   = (__bf16*)alloc((size_t)BH*2);
    __bf16* hbB   = (__bf16*)alloc((size_t)BH*2);
    float* hf     = (float*) alloc((size_t)BH*4);
    float* bufh   = (float*) alloc((size_t)KWIN*BH*4);
    float* bufd   = (float*) alloc((size_t)KWIN*BATCH*4);
    float* locdis = (float*) alloc((size_t)BATCH*KWIN*4);
    float* lh     = (float*) alloc((size_t)BATCH*HDIM*KWIN*4);
    float* mh     = (float*) alloc((size_t)BH*4);
    float* th1    = (float*) alloc((size_t)BATCH*SDIM*4);
    float* theme  = (float*) alloc((size_t)BH*4);
    float* convb  = (float*) alloc((size_t)BH*4);
    unsigned* bar = (unsigned*)alloc(256);

    init_state<<<dim3(BH/256), dim3(256), 0, stream>>>(hbA, bar);
    cast_x<<<dim3((T_STEPS*BATCH*FDIM)/4/256), dim3(256), 0, stream>>>(x, xb, T_STEPS*BATCH*FDIM);
    pack_w_gate<<<dim3((KA/8)*NGC/256), dim3(256), 0, stream>>>(Wk, bk, Wr, br, Bg, cg);
    pack_w_head<<<dim3((KA/8)*16/256), dim3(256), 0, stream>>>(Wk, bk, Wr, br, Bh, ch);

    {
        void* args[] = { (void*)&xb, (void*)&Bg, (void*)&Bh, (void*)&cg, (void*)&ch,
                         (void*)&hbA, (void*)&hbB, (void*)&bufh, (void*)&bufd, (void*)&hf,
                         (void*)&bar };
        hipLaunchCooperativeKernel((void*)persist, dim3(NBLK), dim3(NTHR), args, 0, stream);
    }

    final_locdis<<<dim3(1),   dim3(256), 0, stream>>>(bufd, locdis);
    final_lh    <<<dim3(BH/256), dim3(256), 0, stream>>>(bufh, locdis, lh, mh);
    final_conv  <<<dim3(96),  dim3(256), 0, stream>>>(lh, Wc, bc, convb);
    final_th1   <<<dim3(BATCH*SDIM/256), dim3(256), 0, stream>>>(mh, Ws, bs, th1);
    final_theme <<<dim3(BH/256), dim3(256), 0, stream>>>(th1, Wrs, brs, theme);
    final_out   <<<dim3(BATCH), dim3(64), 0, stream>>>(theme, convb, hf, Wo, bo, out);
}

// Round 4
// 9718.841 us; speedup vs baseline: 1.1206x; 1.1206x over previous
//
#include <hip/hip_runtime.h>
#include <hip/hip_bf16.h>
#include <math.h>

#define T_STEPS 256
#define BATCH   256
#define FDIM    128
#define HDIM    384
#define KWIN    10
#define GDIM    1542
#define SDIM    64
#define NGC     1536   // packed gate cols: col' = ugrp*64 + gate*16 + (u%16)
#define KA      512    // GEMM K = HDIM + FDIM (bias rows folded)
#define BH      (BATCH*HDIM)   // 98304
#define NRG     8      // rowgroups (32 rows each)
#define NCG     24     // colgroups (16 units each)
#define NBLK    (NRG*NCG)
#define NTHR    320    // 5 waves

typedef __bf16 bf16x8 __attribute__((ext_vector_type(8)));
typedef float  f32x4  __attribute__((ext_vector_type(4)));

__device__ __forceinline__ float sigmoidf_(float x){ return 1.f/(1.f+__expf(-x)); }

// ---------------- init: zero h ping buffer + barrier flags ----------------
__global__ void init_state(__bf16* __restrict__ hbA, unsigned* __restrict__ flags){
    int i = blockIdx.x*256 + threadIdx.x;   // BH threads
    hbA[i] = (__bf16)0.f;
    if (i < NRG*32) flags[i] = 0u;
}

// ---------------- cast x (T*B*F fp32) -> bf16 ----------------
__global__ void cast_x(const float* __restrict__ x, __bf16* __restrict__ xb, int n){
    int i = (blockIdx.x*256 + threadIdx.x)*4;
    if (i < n){
        float4 v = *(const float4*)(x+i);
        xb[i+0]=(__bf16)v.x; xb[i+1]=(__bf16)v.y; xb[i+2]=(__bf16)v.z; xb[i+3]=(__bf16)v.w;
    }
}

// ---------------- pack gate weights: Bg[k8][col'][8], col' = ugrp*64+gate*16+um ----------------
__global__ void pack_w_gate(const float* __restrict__ Wk, const float* __restrict__ bk,
                            const float* __restrict__ Wr, const float* __restrict__ br,
                            __bf16* __restrict__ Bg, float* __restrict__ cg){
    int gid = blockIdx.x*256 + threadIdx.x;    // 64*1536 = 98304
    int k8  = gid / NGC;
    int col = gid - k8*NGC;
    int ugrp = col >> 6;
    int rem  = col & 63;
    int gate = rem >> 4;
    int um   = rem & 15;
    int u    = ugrp*16 + um;
    int g    = 6 + gate*HDIM + u;
    bf16x8 out;
    #pragma unroll
    for (int j=0;j<8;++j){
        int k = k8*8 + j;
        float v = (k < HDIM) ? Wr[k*GDIM + g] : Wk[(k-HDIM)*GDIM + g];
        out[j] = (__bf16)v;
    }
    *(bf16x8*)(Bg + (size_t)gid*8) = out;
    if (k8 == 0)
        cg[col] = Wk[FDIM*GDIM + g] + bk[g] + Wr[HDIM*GDIM + g] + br[g];
}

// ---------------- pack head weights: Bh[k8][16][8] (cols 0..5 valid) ----------------
__global__ void pack_w_head(const float* __restrict__ Wk, const float* __restrict__ bk,
                            const float* __restrict__ Wr, const float* __restrict__ br,
                            __bf16* __restrict__ Bh, float* __restrict__ ch){
    int gid = blockIdx.x*256 + threadIdx.x;    // 64*16 = 1024
    int k8  = gid >> 4;
    int colh = gid & 15;
    bf16x8 out;
    #pragma unroll
    for (int j=0;j<8;++j){
        int k = k8*8 + j;
        float v = 0.f;
        if (colh < 6) v = (k < HDIM) ? Wr[k*GDIM + colh] : Wk[(k-HDIM)*GDIM + colh];
        out[j] = (__bf16)v;
    }
    *(bf16x8*)(Bh + (size_t)gid*8) = out;
    if (k8 == 0)
        ch[colh] = (colh < 6) ? (Wk[FDIM*GDIM + colh] + bk[colh] + Wr[HDIM*GDIM + colh] + br[colh]) : 0.f;
}

// ---------------- persistent recurrence kernel ----------------
// 192 blocks x 320 threads. block = (rowgroup rg: 32 rows) x (colgroup cgp: 16 units)
// waves 0-3: gate `wave` for the 16 units, full K in registers (64 VGPR)
// wave 4  : head (6 cols), full K in registers
// Sync: per-rowgroup only (24 blocks) — batch rows never couple across rowgroups.
// RMW-free barrier: arrival = epoch store to own flag; wait = 24 parallel lane polls.
__global__ void __launch_bounds__(NTHR, 1) persist(
    const __bf16* __restrict__ xb, const __bf16* __restrict__ Bg, const __bf16* __restrict__ Bh,
    const float* __restrict__ cg, const float* __restrict__ ch,
    __bf16* __restrict__ hbA, __bf16* __restrict__ hbB,
    float* __restrict__ bufh, float* __restrict__ bufd, float* __restrict__ hf,
    unsigned* __restrict__ flags)
{
    __shared__ __bf16 Alds[32*512];        // 32 KB, XOR-swizzled rows
    __shared__ float  accG[4][32][17];     // gate pre-acts (+bias), padded stride
    __shared__ float  headL[32][8];        // raw head pre-acts (+bias)

    const int tid  = threadIdx.x;
    const int wave = tid >> 6, lane = tid & 63;
    const int rg   = blockIdx.x / NCG, cgp = blockIdx.x % NCG;
    const int row0 = rg * 32;
    const int ccol = lane & 15, krow = lane >> 4;
    unsigned* myflags = flags + rg*32;     // 24 used, padded to 32

    // ---- load weights into registers (persist across all 256 steps) ----
    bf16x8 wfrag[16];
    float biasv;
    if (wave < 4){
        int colb = cgp*64 + wave*16;
        #pragma unroll
        for (int ks=0; ks<16; ++ks)
            wfrag[ks] = *(const bf16x8*)(Bg + (((size_t)ks*4 + krow)*NGC + colb + ccol)*8);
        biasv = cg[colb + ccol];
    } else {
        #pragma unroll
        for (int ks=0; ks<16; ++ks)
            wfrag[ks] = *(const bf16x8*)(Bh + (((size_t)ks*4 + krow)*16 + ccol)*8);
        biasv = ch[ccol];
    }

    float creg0 = 0.f, creg1 = 0.f;        // register-resident cell state (2 rows/thread)
    unsigned ep = 0;

    for (int t=0; t<T_STEPS; ++t){
        const __bf16* hbp = (t & 1) ? hbB : hbA;
        __bf16*       hbn = (t & 1) ? hbA : hbB;

        // ---- stage A = [h | x_t] rows row0..row0+31 into LDS (swizzled) ----
        for (int q = tid; q < 2048; q += NTHR){
            int r  = q >> 6;
            int kk = q & 63;
            int grow = row0 + r;
            bf16x8 v;
            if (kk < 48) v = *(const bf16x8*)(hbp + (size_t)grow*HDIM + kk*8);
            else         v = *(const bf16x8*)(xb + ((size_t)t*BATCH + grow)*FDIM + (kk-48)*8);
            int ei = (r*512 + kk*8) ^ ((r & 7) << 3);
            *(bf16x8*)(Alds + ei) = v;
        }
        __syncthreads();

        // ---- MFMA: 2 M-tiles x 16 k-steps, B from registers ----
        f32x4 acc0 = {}, acc1 = {};
        #pragma unroll
        for (int ks=0; ks<16; ++ks){
            int kbase = ks*32 + krow*8;
            int e0 = ( ccol      *512 + kbase) ^ ((ccol & 7) << 3);
            int e1 = ((ccol + 16)*512 + kbase) ^ ((ccol & 7) << 3);
            bf16x8 a0 = *(const bf16x8*)(Alds + e0);
            bf16x8 a1 = *(const bf16x8*)(Alds + e1);
            acc0 = __builtin_amdgcn_mfma_f32_16x16x32_bf16(a0, wfrag[ks], acc0, 0,0,0);
            acc1 = __builtin_amdgcn_mfma_f32_16x16x32_bf16(a1, wfrag[ks], acc1, 0,0,0);
        }

        // ---- scatter pre-activations to LDS (C/D: col=lane&15, row=krow*4+i) ----
        if (wave < 4){
            #pragma unroll
            for (int i=0;i<4;++i){
                accG[wave][krow*4+i     ][ccol] = acc0[i] + biasv;
                accG[wave][krow*4+i + 16][ccol] = acc1[i] + biasv;
            }
        } else if (ccol < 6){
            #pragma unroll
            for (int i=0;i<4;++i){
                headL[krow*4+i     ][ccol] = acc0[i] + biasv;
                headL[krow*4+i + 16][ccol] = acc1[i] + biasv;
            }
        }
        __syncthreads();

        // ---- gates + state update: 256 threads x 2 rows, c in registers ----
        if (tid < 256){
            int ul = tid & 15;
            int rb = (tid >> 4) * 2;
            int slot = t - (T_STEPS - KWIN);
            #pragma unroll
            for (int j=0; j<2; ++j){
                int r = rb + j;
                int grow = row0 + r;
                float a0 = headL[r][0], a1 = headL[r][1], a2 = headL[r][2];
                float b0 = headL[r][3], b1 = headL[r][4], b2 = headL[r][5];
                float m1v = fmaxf(fmaxf(a0,a1),a2);
                float e0=__expf(a0-m1v), e1=__expf(a1-m1v), e2=__expf(a2-m1v);
                float inv = 1.f/(e0+e1+e2);
                float fm0 = e0*inv, fm1 = fm0 + e1*inv, fm2 = fm1 + e2*inv;
                float m2v = fmaxf(fmaxf(b0,b1),b2);
                float f0=__expf(b0-m2v), f1=__expf(b1-m2v), f2=__expf(b2-m2v);
                float inv2 = 1.f/(f0+f1+f2);
                float im2 = f2*inv2, im1 = im2 + f1*inv2, im0 = im1 + f0*inv2;
                int u = cgp*16 + ul;
                int l = u >> 7;
                float fml = (l==0)?fm0:((l==1)?fm1:fm2);
                float iml = (l==0)?im0:((l==1)?im1:im2);
                float fg = sigmoidf_(accG[0][r][ul]);
                float ig = sigmoidf_(accG[1][r][ul]);
                float og = sigmoidf_(accG[2][r][ul]);
                float ci = tanhf   (accG[3][r][ul]);
                float cold = j ? creg1 : creg0;
                float ov = fml*iml;
                float cn = ov*(fg*cold + ig*ci) + (fml-ov)*cold + (iml-ov)*ci;
                float h  = og * tanhf(cn);
                if (j) creg1 = cn; else creg0 = cn;
                size_t idx = (size_t)grow*HDIM + u;
                hbn[idx] = (__bf16)h;
                if (slot >= 0) bufh[(size_t)slot*BH + idx] = h;
                if (t == T_STEPS-1) hf[idx] = h;
                if (slot >= 0 && cgp == 0 && ul == 0)
                    bufd[slot*BATCH + grow] = 1.f - (fm0+fm1+fm2)*(1.f/3.f);
            }
        }

        // ---- per-rowgroup RMW-free barrier (24 blocks) ----
        ++ep;
        __threadfence();                   // release: drain this thread's h stores
        __syncthreads();                   // all threads of block fenced
        if (tid == 0)
            __hip_atomic_store(&myflags[cgp], ep, __ATOMIC_RELEASE, __HIP_MEMORY_SCOPE_AGENT);
        if (wave == 0 && lane < NCG){
            while (__hip_atomic_load(&myflags[lane], __ATOMIC_RELAXED, __HIP_MEMORY_SCOPE_AGENT) < ep)
                __builtin_amdgcn_s_sleep(2);
        }
        __syncthreads();
        __threadfence();                   // acquire: invalidate so next h reads are fresh
    }
}

// ---------------- finals ----------------
__global__ void final_locdis(const float* __restrict__ bufd, float* __restrict__ locdis){
    int b = threadIdx.x;   // 256
    float d[KWIN]; float cum = 0.f;
    #pragma unroll
    for (int k=0;k<KWIN;++k){ cum += bufd[k*BATCH + b]; d[k] = cum; }
    float m = d[0];
    #pragma unroll
    for (int k=1;k<KWIN;++k) m = fmaxf(m, d[k]);
    float s = 0.f;
    #pragma unroll
    for (int k=0;k<KWIN;++k){ d[k] = __expf(d[k]-m); s += d[k]; }
    float invs = 1.f/s;
    #pragma unroll
    for (int k=0;k<KWIN;++k) locdis[b*KWIN + k] = d[k]*invs;
}

__global__ void final_lh(const float* __restrict__ bufh, const float* __restrict__ locdis,
                         float* __restrict__ lh, float* __restrict__ mh){
    int gid = blockIdx.x*256 + threadIdx.x;    // BH
    int b = gid / HDIM;
    int i = gid - b*HDIM;
    float s = 0.f;
    #pragma unroll
    for (int k=0;k<KWIN;++k){
        float v = bufh[(size_t)k*BH + gid] * locdis[b*KWIN + k];
        lh[(size_t)b*(HDIM*KWIN) + i*KWIN + k] = v;
        s += v;
    }
    mh[gid] = s * (1.f/KWIN);
}

__global__ __launch_bounds__(256) void final_conv(const float* __restrict__ lh, const float* __restrict__ Wc,
                                                  const float* __restrict__ bc, float* __restrict__ cvout){
    __shared__ float As[32*257];
    __shared__ float Bs[32*257];
    int tid = threadIdx.x;
    int bb = blockIdx.x / 12, ob = blockIdx.x % 12;   // 8 x 12 = 96 blocks
    int tx = tid & 15, ty = tid >> 4;
    float acc00=0.f, acc01=0.f, acc10=0.f, acc11=0.f;
    const int KD = HDIM*KWIN;   // 3840 = 15 * 256
    for (int ch=0; ch<15; ++ch){
        #pragma unroll
        for (int p=0;p<8;++p){
            int q   = tid + p*256;
            int row = q >> 6;
            int c4  = q & 63;
            float4 va = *(const float4*)(lh + (size_t)(bb*32+row)*KD + ch*256 + c4*4);
            float4 vb = *(const float4*)(Wc + (size_t)(ob*32+row)*KD + ch*256 + c4*4);
            int o = row*257 + c4*4;
            As[o+0]=va.x; As[o+1]=va.y; As[o+2]=va.z; As[o+3]=va.w;
            Bs[o+0]=vb.x; Bs[o+1]=vb.y; Bs[o+2]=vb.z; Bs[o+3]=vb.w;
        }
        __syncthreads();
        for (int kk=0; kk<256; ++kk){
            float x0 = As[ty*257+kk],      x1 = As[(ty+16)*257+kk];
            float w0 = Bs[tx*257+kk],      w1 = Bs[(tx+16)*257+kk];
            acc00 += x0*w0; acc01 += x0*w1; acc10 += x1*w0; acc11 += x1*w1;
        }
        __syncthreads();
    }
    int r0 = bb*32+ty, r1 = r0+16, o0 = ob*32+tx, o1 = o0+16;
    cvout[(size_t)r0*HDIM + o0] = acc00 + bc[o0];
    cvout[(size_t)r0*HDIM + o1] = acc01 + bc[o1];
    cvout[(size_t)r1*HDIM + o0] = acc10 + bc[o0];
    cvout[(size_t)r1*HDIM + o1] = acc11 + bc[o1];
}

__global__ void final_th1(const float* __restrict__ mh, const float* __restrict__ Ws,
                          const float* __restrict__ bs, float* __restrict__ th1){
    int gid = blockIdx.x*256 + threadIdx.x;   // 256*64
    int b = gid >> 6, s = gid & 63;
    float acc = bs[s];
    const float* mr = mh + (size_t)b*HDIM;
    for (int i=0;i<HDIM;++i) acc += mr[i] * Ws[i*SDIM + s];
    th1[gid] = fmaxf(acc, 0.f);
}

__global__ void final_theme(const float* __restrict__ th1, const float* __restrict__ Wrs,
                            const float* __restrict__ brs, float* __restrict__ theme){
    int gid = blockIdx.x*256 + threadIdx.x;   // BH
    int b = gid / HDIM, o = gid - b*HDIM;
    float acc = brs[o];
    const float* tr = th1 + b*SDIM;
    for (int j=0;j<SDIM;++j) acc += tr[j] * Wrs[j*HDIM + o];
    theme[gid] = sigmoidf_(acc);
}

__global__ void final_out(const float* __restrict__ theme, const float* __restrict__ cvout,
                          const float* __restrict__ hf, const float* __restrict__ Wo,
                          const float* __restrict__ bo, float* __restrict__ out){
    int b = blockIdx.x, lane = threadIdx.x;   // 256 blocks x 64 threads
    float s = 0.f;
    for (int u=lane; u<HDIM; u+=64){
        float r = theme[(size_t)b*HDIM+u]*cvout[(size_t)b*HDIM+u] + hf[(size_t)b*HDIM+u];
        s += r * Wo[u];
    }
    #pragma unroll
    for (int off=32; off; off>>=1) s += __shfl_down(s, off);
    if (lane == 0) out[b] = sigmoidf_(s + bo[0]);
}

extern "C" void kernel_launch(void* const* d_in, const int* in_sizes, int n_in,
                              void* d_out, int out_size, void* d_ws, size_t ws_size,
                              hipStream_t stream){
    const float* x   = (const float*)d_in[0];
    const float* Wk  = (const float*)d_in[1];
    const float* bk  = (const float*)d_in[2];
    const float* Wr  = (const float*)d_in[3];
    const float* br  = (const float*)d_in[4];
    const float* Ws  = (const float*)d_in[5];
    const float* bs  = (const float*)d_in[6];
    const float* Wrs = (const float*)d_in[7];
    const float* brs = (const float*)d_in[8];
    const float* Wc  = (const float*)d_in[9];
    const float* bc  = (const float*)d_in[10];
    const float* Wo  = (const float*)d_in[11];
    const float* bo  = (const float*)d_in[12];
    float* out = (float*)d_out;

    char* w = (char*)d_ws;
    auto alloc = [&](size_t bytes)->char*{ char* p = w; w += (bytes + 255) & ~(size_t)255; return p; };
    __bf16* xb    = (__bf16*)alloc((size_t)T_STEPS*BATCH*FDIM*2);   // 16.8 MB
    __bf16* Bg    = (__bf16*)alloc((size_t)(KA/8)*NGC*8*2);         // 1.57 MB
    __bf16* Bh    = (__bf16*)alloc((size_t)(KA/8)*16*8*2);          // 16 KB
    float* cg     = (float*) alloc(NGC*4);
    float* ch     = (float*) alloc(16*4);
    __bf16* hbA   = (__bf16*)alloc((size_t)BH*2);
    __bf16* hbB   = (__bf16*)alloc((size_t)BH*2);
    float* hf     = (float*) alloc((size_t)BH*4);
    float* bufh   = (float*) alloc((size_t)KWIN*BH*4);
    float* bufd   = (float*) alloc((size_t)KWIN*BATCH*4);
    float* locdis = (float*) alloc((size_t)BATCH*KWIN*4);
    float* lh     = (float*) alloc((size_t)BATCH*HDIM*KWIN*4);
    float* mh     = (float*) alloc((size_t)BH*4);
    float* th1    = (float*) alloc((size_t)BATCH*SDIM*4);
    float* theme  = (float*) alloc((size_t)BH*4);
    float* convb  = (float*) alloc((size_t)BH*4);
    unsigned* flags = (unsigned*)alloc(NRG*32*4);

    init_state<<<dim3(BH/256), dim3(256), 0, stream>>>(hbA, flags);
    cast_x<<<dim3((T_STEPS*BATCH*FDIM)/4/256), dim3(256), 0, stream>>>(x, xb, T_STEPS*BATCH*FDIM);
    pack_w_gate<<<dim3((KA/8)*NGC/256), dim3(256), 0, stream>>>(Wk, bk, Wr, br, Bg, cg);
    pack_w_head<<<dim3((KA/8)*16/256), dim3(256), 0, stream>>>(Wk, bk, Wr, br, Bh, ch);

    {
        void* xbp=(void*)xb;
        void* args[] = { &xbp, (void*)&Bg, (void*)&Bh, (void*)&cg, (void*)&ch,
                         (void*)&hbA, (void*)&hbB, (void*)&bufh, (void*)&bufd, (void*)&hf,
                         (void*)&flags };
        args[0] = (void*)&xb;
        hipLaunchCooperativeKernel((void*)persist, dim3(NBLK), dim3(NTHR), args, 0, stream);
    }

    final_locdis<<<dim3(1),   dim3(256), 0, stream>>>(bufd, locdis);
    final_lh    <<<dim3(BH/256), dim3(256), 0, stream>>>(bufh, locdis, lh, mh);
    final_conv  <<<dim3(96),  dim3(256), 0, stream>>>(lh, Wc, bc, convb);
    final_th1   <<<dim3(BATCH*SDIM/256), dim3(256), 0, stream>>>(mh, Ws, bs, th1);
    final_theme <<<dim3(BH/256), dim3(256), 0, stream>>>(th1, Wrs, brs, theme);
    final_out   <<<dim3(BATCH), dim3(64), 0, stream>>>(theme, convb, hf, Wo, bo, out);
}

// Round 5
// 2029.059 us; speedup vs baseline: 5.3674x; 4.7898x over previous
//
#include <hip/hip_runtime.h>
#include <hip/hip_bf16.h>
#include <math.h>

#define T_STEPS 256
#define BATCH   256
#define FDIM    128
#define HDIM    384
#define KWIN    10
#define GDIM    1542
#define SDIM    64
#define NGC     1536   // packed gate cols: col' = ugrp*64 + gate*16 + (u%16)
#define KA      512    // GEMM K = HDIM + FDIM (bias rows folded)
#define BH      (BATCH*HDIM)   // 98304
#define NRG     8      // rowgroups (32 rows each)
#define NCG     24     // colgroups (16 units each)
#define NBLK    (NRG*NCG)
#define NTHR    320    // 5 waves

typedef __bf16 bf16x8 __attribute__((ext_vector_type(8)));
typedef float  f32x4  __attribute__((ext_vector_type(4)));

__device__ __forceinline__ float sigmoidf_(float x){ return 1.f/(1.f+__expf(-x)); }

// ---------------- init: zero h ping buffer + barrier flags ----------------
__global__ void init_state(__bf16* __restrict__ hbA, unsigned* __restrict__ flags){
    int i = blockIdx.x*256 + threadIdx.x;   // BH threads
    hbA[i] = (__bf16)0.f;
    if (i < NRG*32) flags[i] = 0u;
}

// ---------------- cast x (T*B*F fp32) -> bf16 ----------------
__global__ void cast_x(const float* __restrict__ x, __bf16* __restrict__ xb, int n){
    int i = (blockIdx.x*256 + threadIdx.x)*4;
    if (i < n){
        float4 v = *(const float4*)(x+i);
        xb[i+0]=(__bf16)v.x; xb[i+1]=(__bf16)v.y; xb[i+2]=(__bf16)v.z; xb[i+3]=(__bf16)v.w;
    }
}

// ---------------- pack gate weights: Bg[k8][col'][8], col' = ugrp*64+gate*16+um ----------------
__global__ void pack_w_gate(const float* __restrict__ Wk, const float* __restrict__ bk,
                            const float* __restrict__ Wr, const float* __restrict__ br,
                            __bf16* __restrict__ Bg, float* __restrict__ cg){
    int gid = blockIdx.x*256 + threadIdx.x;    // 64*1536 = 98304
    int k8  = gid / NGC;
    int col = gid - k8*NGC;
    int ugrp = col >> 6;
    int rem  = col & 63;
    int gate = rem >> 4;
    int um   = rem & 15;
    int u    = ugrp*16 + um;
    int g    = 6 + gate*HDIM + u;
    bf16x8 out;
    #pragma unroll
    for (int j=0;j<8;++j){
        int k = k8*8 + j;
        float v = (k < HDIM) ? Wr[k*GDIM + g] : Wk[(k-HDIM)*GDIM + g];
        out[j] = (__bf16)v;
    }
    *(bf16x8*)(Bg + (size_t)gid*8) = out;
    if (k8 == 0)
        cg[col] = Wk[FDIM*GDIM + g] + bk[g] + Wr[HDIM*GDIM + g] + br[g];
}

// ---------------- pack head weights: Bh[k8][16][8] (cols 0..5 valid) ----------------
__global__ void pack_w_head(const float* __restrict__ Wk, const float* __restrict__ bk,
                            const float* __restrict__ Wr, const float* __restrict__ br,
                            __bf16* __restrict__ Bh, float* __restrict__ ch){
    int gid = blockIdx.x*256 + threadIdx.x;    // 64*16 = 1024
    int k8  = gid >> 4;
    int colh = gid & 15;
    bf16x8 out;
    #pragma unroll
    for (int j=0;j<8;++j){
        int k = k8*8 + j;
        float v = 0.f;
        if (colh < 6) v = (k < HDIM) ? Wr[k*GDIM + colh] : Wk[(k-HDIM)*GDIM + colh];
        out[j] = (__bf16)v;
    }
    *(bf16x8*)(Bh + (size_t)gid*8) = out;
    if (k8 == 0)
        ch[colh] = (colh < 6) ? (Wk[FDIM*GDIM + colh] + bk[colh] + Wr[HDIM*GDIM + colh] + br[colh]) : 0.f;
}

// ---------------- persistent recurrence kernel ----------------
// 192 blocks x 320 threads. block = (rowgroup rg: 32 rows) x (colgroup cgp: 16 units)
// waves 0-3: gate `wave` for its 16 units, full K in registers; wave 4: head (6 cols).
// Cross-block data (h ping-pong, flags) uses RELAXED AGENT atomics only (sc0sc1 -> L3,
// cross-XCD coherent). NO __threadfence anywhere in the loop: fences emit buffer_wbl2/
// buffer_inv L2 cache-walks (~tens of us/step, the R3/R4 bottleneck). Ordering comes
// from __syncthreads' per-wave vmcnt(0) drain (stores L3-acked) before the flag store.
__global__ void __launch_bounds__(NTHR, 1) persist(
    const __bf16* __restrict__ xb, const __bf16* __restrict__ Bg, const __bf16* __restrict__ Bh,
    const float* __restrict__ cg, const float* __restrict__ ch,
    __bf16* __restrict__ hbA, __bf16* __restrict__ hbB,
    float* __restrict__ bufh, float* __restrict__ bufd, float* __restrict__ hf,
    unsigned* __restrict__ flags)
{
    __shared__ __bf16 Alds[32*512];        // 32 KB, XOR-swizzled rows
    __shared__ float  accG[4][32][17];     // gate pre-acts (+bias), padded stride
    __shared__ float  headL[32][8];        // raw head pre-acts (+bias)

    const int tid  = threadIdx.x;
    const int wave = tid >> 6, lane = tid & 63;
    const int rg   = blockIdx.x / NCG, cgp = blockIdx.x % NCG;
    const int row0 = rg * 32;
    const int ccol = lane & 15, krow = lane >> 4;
    unsigned* myflags = flags + rg*32;     // 24 used, padded to 32

    // ---- load weights into registers (persist across all 256 steps) ----
    bf16x8 wfrag[16];
    float biasv;
    if (wave < 4){
        int colb = cgp*64 + wave*16;
        #pragma unroll
        for (int ks=0; ks<16; ++ks)
            wfrag[ks] = *(const bf16x8*)(Bg + (((size_t)ks*4 + krow)*NGC + colb + ccol)*8);
        biasv = cg[colb + ccol];
    } else {
        #pragma unroll
        for (int ks=0; ks<16; ++ks)
            wfrag[ks] = *(const bf16x8*)(Bh + (((size_t)ks*4 + krow)*16 + ccol)*8);
        biasv = ch[ccol];
    }

    float creg0 = 0.f, creg1 = 0.f;        // register-resident cell state (2 rows/thread)
    unsigned ep = 0;

    for (int t=0; t<T_STEPS; ++t){
        const __bf16* hbp = (t & 1) ? hbB : hbA;
        __bf16*       hbn = (t & 1) ? hbA : hbB;

        // ---- stage A = [h | x_t] rows row0..row0+31 into LDS (swizzled) ----
        // h part: coherent (agent-relaxed) 8B loads from L3; x part: normal cached loads.
        for (int q = tid; q < 2048; q += NTHR){
            int r  = q >> 6;
            int kk = q & 63;
            int grow = row0 + r;
            int ei = (r*512 + kk*8) ^ ((r & 7) << 3);
            if (kk < 48){
                unsigned long long* hp8 = (unsigned long long*)(hbp + (size_t)grow*HDIM + kk*8);
                unsigned long long u0 = __hip_atomic_load(hp8,   __ATOMIC_RELAXED, __HIP_MEMORY_SCOPE_AGENT);
                unsigned long long u1 = __hip_atomic_load(hp8+1, __ATOMIC_RELAXED, __HIP_MEMORY_SCOPE_AGENT);
                *((unsigned long long*)(Alds + ei)    ) = u0;
                *((unsigned long long*)(Alds + ei) + 1) = u1;
            } else {
                bf16x8 v = *(const bf16x8*)(xb + ((size_t)t*BATCH + grow)*FDIM + (kk-48)*8);
                *(bf16x8*)(Alds + ei) = v;
            }
        }
        __syncthreads();

        // ---- MFMA: 2 M-tiles x 16 k-steps, B from registers ----
        f32x4 acc0 = {}, acc1 = {};
        #pragma unroll
        for (int ks=0; ks<16; ++ks){
            int kbase = ks*32 + krow*8;
            int e0 = ( ccol      *512 + kbase) ^ ((ccol & 7) << 3);
            int e1 = ((ccol + 16)*512 + kbase) ^ ((ccol & 7) << 3);
            bf16x8 a0 = *(const bf16x8*)(Alds + e0);
            bf16x8 a1 = *(const bf16x8*)(Alds + e1);
            acc0 = __builtin_amdgcn_mfma_f32_16x16x32_bf16(a0, wfrag[ks], acc0, 0,0,0);
            acc1 = __builtin_amdgcn_mfma_f32_16x16x32_bf16(a1, wfrag[ks], acc1, 0,0,0);
        }

        // ---- scatter pre-activations to LDS (C/D: col=lane&15, row=krow*4+i) ----
        if (wave < 4){
            #pragma unroll
            for (int i=0;i<4;++i){
                accG[wave][krow*4+i     ][ccol] = acc0[i] + biasv;
                accG[wave][krow*4+i + 16][ccol] = acc1[i] + biasv;
            }
        } else if (ccol < 6){
            #pragma unroll
            for (int i=0;i<4;++i){
                headL[krow*4+i     ][ccol] = acc0[i] + biasv;
                headL[krow*4+i + 16][ccol] = acc1[i] + biasv;
            }
        }
        __syncthreads();

        // ---- gates + state update: 256 threads x 2 rows, c in registers ----
        if (tid < 256){
            int ul = tid & 15;
            int rb = (tid >> 4) * 2;
            int slot = t - (T_STEPS - KWIN);
            #pragma unroll
            for (int j=0; j<2; ++j){
                int r = rb + j;
                int grow = row0 + r;
                float a0 = headL[r][0], a1 = headL[r][1], a2 = headL[r][2];
                float b0 = headL[r][3], b1 = headL[r][4], b2 = headL[r][5];
                float m1v = fmaxf(fmaxf(a0,a1),a2);
                float e0=__expf(a0-m1v), e1=__expf(a1-m1v), e2=__expf(a2-m1v);
                float inv = 1.f/(e0+e1+e2);
                float fm0 = e0*inv, fm1 = fm0 + e1*inv, fm2 = fm1 + e2*inv;
                float m2v = fmaxf(fmaxf(b0,b1),b2);
                float f0=__expf(b0-m2v), f1=__expf(b1-m2v), f2=__expf(b2-m2v);
                float inv2 = 1.f/(f0+f1+f2);
                float im2 = f2*inv2, im1 = im2 + f1*inv2, im0 = im1 + f0*inv2;
                int u = cgp*16 + ul;
                int l = u >> 7;
                float fml = (l==0)?fm0:((l==1)?fm1:fm2);
                float iml = (l==0)?im0:((l==1)?im1:im2);
                float fg = sigmoidf_(accG[0][r][ul]);
                float ig = sigmoidf_(accG[1][r][ul]);
                float og = sigmoidf_(accG[2][r][ul]);
                float ci = tanhf   (accG[3][r][ul]);
                float cold = j ? creg1 : creg0;
                float ov = fml*iml;
                float cn = ov*(fg*cold + ig*ci) + (fml-ov)*cold + (iml-ov)*ci;
                float h  = og * tanhf(cn);
                if (j) creg1 = cn; else creg0 = cn;
                size_t idx = (size_t)grow*HDIM + u;

                // coherent h store: pair adjacent columns (even lane stores 4B)
                unsigned short hu = __builtin_bit_cast(unsigned short, (__bf16)h);
                unsigned short hp = (unsigned short)__shfl_xor((int)hu, 1);
                if ((ul & 1) == 0){
                    unsigned hv = (unsigned)hu | ((unsigned)hp << 16);
                    __hip_atomic_store((unsigned*)(hbn + (size_t)grow*HDIM + (u & ~1)),
                                       hv, __ATOMIC_RELAXED, __HIP_MEMORY_SCOPE_AGENT);
                }
                if (slot >= 0) bufh[(size_t)slot*BH + idx] = h;    // read post-kernel only
                if (t == T_STEPS-1) hf[idx] = h;
                if (slot >= 0 && cgp == 0 && ul == 0)
                    bufd[slot*BATCH + grow] = 1.f - (fm0+fm1+fm2)*(1.f/3.f);
            }
        }

        // ---- per-rowgroup fence-free barrier (24 blocks) ----
        ++ep;
        __syncthreads();   // each wave drains vmcnt(0) -> all sc1 h-stores L3-acked
        if (tid == 0)
            __hip_atomic_store(&myflags[cgp], ep, __ATOMIC_RELAXED, __HIP_MEMORY_SCOPE_AGENT);
        if (wave == 0 && lane < NCG){
            while (__hip_atomic_load(&myflags[lane], __ATOMIC_RELAXED, __HIP_MEMORY_SCOPE_AGENT) < ep)
                __builtin_amdgcn_s_sleep(2);
        }
        __syncthreads();
    }
}

// ---------------- finals ----------------
__global__ void final_locdis(const float* __restrict__ bufd, float* __restrict__ locdis){
    int b = threadIdx.x;   // 256
    float d[KWIN]; float cum = 0.f;
    #pragma unroll
    for (int k=0;k<KWIN;++k){ cum += bufd[k*BATCH + b]; d[k] = cum; }
    float m = d[0];
    #pragma unroll
    for (int k=1;k<KWIN;++k) m = fmaxf(m, d[k]);
    float s = 0.f;
    #pragma unroll
    for (int k=0;k<KWIN;++k){ d[k] = __expf(d[k]-m); s += d[k]; }
    float invs = 1.f/s;
    #pragma unroll
    for (int k=0;k<KWIN;++k) locdis[b*KWIN + k] = d[k]*invs;
}

__global__ void final_lh(const float* __restrict__ bufh, const float* __restrict__ locdis,
                         float* __restrict__ lh, float* __restrict__ mh){
    int gid = blockIdx.x*256 + threadIdx.x;    // BH
    int b = gid / HDIM;
    int i = gid - b*HDIM;
    float s = 0.f;
    #pragma unroll
    for (int k=0;k<KWIN;++k){
        float v = bufh[(size_t)k*BH + gid] * locdis[b*KWIN + k];
        lh[(size_t)b*(HDIM*KWIN) + i*KWIN + k] = v;
        s += v;
    }
    mh[gid] = s * (1.f/KWIN);
}

__global__ __launch_bounds__(256) void final_conv(const float* __restrict__ lh, const float* __restrict__ Wc,
                                                  const float* __restrict__ bc, float* __restrict__ cvout){
    __shared__ float As[32*257];
    __shared__ float Bs[32*257];
    int tid = threadIdx.x;
    int bb = blockIdx.x / 12, ob = blockIdx.x % 12;   // 8 x 12 = 96 blocks
    int tx = tid & 15, ty = tid >> 4;
    float acc00=0.f, acc01=0.f, acc10=0.f, acc11=0.f;
    const int KD = HDIM*KWIN;   // 3840 = 15 * 256
    for (int ch=0; ch<15; ++ch){
        #pragma unroll
        for (int p=0;p<8;++p){
            int q   = tid + p*256;
            int row = q >> 6;
            int c4  = q & 63;
            float4 va = *(const float4*)(lh + (size_t)(bb*32+row)*KD + ch*256 + c4*4);
            float4 vb = *(const float4*)(Wc + (size_t)(ob*32+row)*KD + ch*256 + c4*4);
            int o = row*257 + c4*4;
            As[o+0]=va.x; As[o+1]=va.y; As[o+2]=va.z; As[o+3]=va.w;
            Bs[o+0]=vb.x; Bs[o+1]=vb.y; Bs[o+2]=vb.z; Bs[o+3]=vb.w;
        }
        __syncthreads();
        for (int kk=0; kk<256; ++kk){
            float x0 = As[ty*257+kk],      x1 = As[(ty+16)*257+kk];
            float w0 = Bs[tx*257+kk],      w1 = Bs[(tx+16)*257+kk];
            acc00 += x0*w0; acc01 += x0*w1; acc10 += x1*w0; acc11 += x1*w1;
        }
        __syncthreads();
    }
    int r0 = bb*32+ty, r1 = r0+16, o0 = ob*32+tx, o1 = o0+16;
    cvout[(size_t)r0*HDIM + o0] = acc00 + bc[o0];
    cvout[(size_t)r0*HDIM + o1] = acc01 + bc[o1];
    cvout[(size_t)r1*HDIM + o0] = acc10 + bc[o0];
    cvout[(size_t)r1*HDIM + o1] = acc11 + bc[o1];
}

__global__ void final_th1(const float* __restrict__ mh, const float* __restrict__ Ws,
                          const float* __restrict__ bs, float* __restrict__ th1){
    int gid = blockIdx.x*256 + threadIdx.x;   // 256*64
    int b = gid >> 6, s = gid & 63;
    float acc = bs[s];
    const float* mr = mh + (size_t)b*HDIM;
    for (int i=0;i<HDIM;++i) acc += mr[i] * Ws[i*SDIM + s];
    th1[gid] = fmaxf(acc, 0.f);
}

__global__ void final_theme(const float* __restrict__ th1, const float* __restrict__ Wrs,
                            const float* __restrict__ brs, float* __restrict__ theme){
    int gid = blockIdx.x*256 + threadIdx.x;   // BH
    int b = gid / HDIM, o = gid - b*HDIM;
    float acc = brs[o];
    const float* tr = th1 + b*SDIM;
    for (int j=0;j<SDIM;++j) acc += tr[j] * Wrs[j*HDIM + o];
    theme[gid] = sigmoidf_(acc);
}

__global__ void final_out(const float* __restrict__ theme, const float* __restrict__ cvout,
                          const float* __restrict__ hf, const float* __restrict__ Wo,
                          const float* __restrict__ bo, float* __restrict__ out){
    int b = blockIdx.x, lane = threadIdx.x;   // 256 blocks x 64 threads
    float s = 0.f;
    for (int u=lane; u<HDIM; u+=64){
        float r = theme[(size_t)b*HDIM+u]*cvout[(size_t)b*HDIM+u] + hf[(size_t)b*HDIM+u];
        s += r * Wo[u];
    }
    #pragma unroll
    for (int off=32; off; off>>=1) s += __shfl_down(s, off);
    if (lane == 0) out[b] = sigmoidf_(s + bo[0]);
}

extern "C" void kernel_launch(void* const* d_in, const int* in_sizes, int n_in,
                              void* d_out, int out_size, void* d_ws, size_t ws_size,
                              hipStream_t stream){
    const float* x   = (const float*)d_in[0];
    const float* Wk  = (const float*)d_in[1];
    const float* bk  = (const float*)d_in[2];
    const float* Wr  = (const float*)d_in[3];
    const float* br  = (const float*)d_in[4];
    const float* Ws  = (const float*)d_in[5];
    const float* bs  = (const float*)d_in[6];
    const float* Wrs = (const float*)d_in[7];
    const float* brs = (const float*)d_in[8];
    const float* Wc  = (const float*)d_in[9];
    const float* bc  = (const float*)d_in[10];
    const float* Wo  = (const float*)d_in[11];
    const float* bo  = (const float*)d_in[12];
    float* out = (float*)d_out;

    char* w = (char*)d_ws;
    auto alloc = [&](size_t bytes)->char*{ char* p = w; w += (bytes + 255) & ~(size_t)255; return p; };
    __bf16* xb    = (__bf16*)alloc((size_t)T_STEPS*BATCH*FDIM*2);   // 16.8 MB
    __bf16* Bg    = (__bf16*)alloc((size_t)(KA/8)*NGC*8*2);         // 1.57 MB
    __bf16* Bh    = (__bf16*)alloc((size_t)(KA/8)*16*8*2);          // 16 KB
    float* cg     = (float*) alloc(NGC*4);
    float* ch     = (float*) alloc(16*4);
    __bf16* hbA   = (__bf16*)alloc((size_t)BH*2);
    __bf16* hbB   = (__bf16*)alloc((size_t)BH*2);
    float* hf     = (float*) alloc((size_t)BH*4);
    float* bufh   = (float*) alloc((size_t)KWIN*BH*4);
    float* bufd   = (float*) alloc((size_t)KWIN*BATCH*4);
    float* locdis = (float*) alloc((size_t)BATCH*KWIN*4);
    float* lh     = (float*) alloc((size_t)BATCH*HDIM*KWIN*4);
    float* mh     = (float*) alloc((size_t)BH*4);
    float* th1    = (float*) alloc((size_t)BATCH*SDIM*4);
    float* theme  = (float*) alloc((size_t)BH*4);
    float* convb  = (float*) alloc((size_t)BH*4);
    unsigned* flags = (unsigned*)alloc(NRG*32*4);

    init_state<<<dim3(BH/256), dim3(256), 0, stream>>>(hbA, flags);
    cast_x<<<dim3((T_STEPS*BATCH*FDIM)/4/256), dim3(256), 0, stream>>>(x, xb, T_STEPS*BATCH*FDIM);
    pack_w_gate<<<dim3((KA/8)*NGC/256), dim3(256), 0, stream>>>(Wk, bk, Wr, br, Bg, cg);
    pack_w_head<<<dim3((KA/8)*16/256), dim3(256), 0, stream>>>(Wk, bk, Wr, br, Bh, ch);

    {
        void* args[] = { (void*)&xb, (void*)&Bg, (void*)&Bh, (void*)&cg, (void*)&ch,
                         (void*)&hbA, (void*)&hbB, (void*)&bufh, (void*)&bufd, (void*)&hf,
                         (void*)&flags };
        hipLaunchCooperativeKernel((void*)persist, dim3(NBLK), dim3(NTHR), args, 0, stream);
    }

    final_locdis<<<dim3(1),   dim3(256), 0, stream>>>(bufd, locdis);
    final_lh    <<<dim3(BH/256), dim3(256), 0, stream>>>(bufh, locdis, lh, mh);
    final_conv  <<<dim3(96),  dim3(256), 0, stream>>>(lh, Wc, bc, convb);
    final_th1   <<<dim3(BATCH*SDIM/256), dim3(256), 0, stream>>>(mh, Ws, bs, th1);
    final_theme <<<dim3(BH/256), dim3(256), 0, stream>>>(th1, Wrs, brs, theme);
    final_out   <<<dim3(BATCH), dim3(64), 0, stream>>>(theme, convb, hf, Wo, bo, out);
}

// Round 6
// 2002.426 us; speedup vs baseline: 5.4387x; 1.0133x over previous
//
#include <hip/hip_runtime.h>
#include <hip/hip_bf16.h>
#include <math.h>

#define T_STEPS 256
#define BATCH   256
#define FDIM    128
#define HDIM    384
#define KWIN    10
#define GDIM    1542
#define SDIM    64
#define NGC     1536   // packed gate cols: col' = ugrp*64 + gate*16 + (u%16)
#define KA      512    // GEMM K = HDIM + FDIM (bias rows folded)
#define BH      (BATCH*HDIM)   // 98304
#define NRG     8      // rowgroups (32 rows each)
#define NCG     24     // colgroups (16 units each)
#define NBLK    (NRG*NCG)
#define NTHR    320    // 5 waves

typedef __bf16 bf16x8 __attribute__((ext_vector_type(8)));
typedef float  f32x4  __attribute__((ext_vector_type(4)));

__device__ __forceinline__ float sigmoidf_(float x){ return 1.f/(1.f+__expf(-x)); }
// fast tanh: exact identity 1 - 2/(e^{2x}+1); correct limits at +/-inf; ~3e-6 rel err
__device__ __forceinline__ float tanhf_(float x){
    float e = __expf(2.f*x);
    return 1.f - 2.f/(e+1.f);
}

// ---------------- init: zero h ping buffer + barrier flags ----------------
__global__ void init_state(__bf16* __restrict__ hbA, unsigned* __restrict__ flags){
    int i = blockIdx.x*256 + threadIdx.x;   // BH threads
    hbA[i] = (__bf16)0.f;
    if (i < NRG*32) flags[i] = 0u;
}

// ---------------- cast x (T*B*F fp32) -> bf16 ----------------
__global__ void cast_x(const float* __restrict__ x, __bf16* __restrict__ xb, int n){
    int i = (blockIdx.x*256 + threadIdx.x)*4;
    if (i < n){
        float4 v = *(const float4*)(x+i);
        xb[i+0]=(__bf16)v.x; xb[i+1]=(__bf16)v.y; xb[i+2]=(__bf16)v.z; xb[i+3]=(__bf16)v.w;
    }
}

// ---------------- pack gate weights: Bg[k8][col'][8], col' = ugrp*64+gate*16+um ----------------
__global__ void pack_w_gate(const float* __restrict__ Wk, const float* __restrict__ bk,
                            const float* __restrict__ Wr, const float* __restrict__ br,
                            __bf16* __restrict__ Bg, float* __restrict__ cg){
    int gid = blockIdx.x*256 + threadIdx.x;    // 64*1536 = 98304
    int k8  = gid / NGC;
    int col = gid - k8*NGC;
    int ugrp = col >> 6;
    int rem  = col & 63;
    int gate = rem >> 4;
    int um   = rem & 15;
    int u    = ugrp*16 + um;
    int g    = 6 + gate*HDIM + u;
    bf16x8 out;
    #pragma unroll
    for (int j=0;j<8;++j){
        int k = k8*8 + j;
        float v = (k < HDIM) ? Wr[k*GDIM + g] : Wk[(k-HDIM)*GDIM + g];
        out[j] = (__bf16)v;
    }
    *(bf16x8*)(Bg + (size_t)gid*8) = out;
    if (k8 == 0)
        cg[col] = Wk[FDIM*GDIM + g] + bk[g] + Wr[HDIM*GDIM + g] + br[g];
}

// ---------------- pack head weights: Bh[k8][16][8] (cols 0..5 valid) ----------------
__global__ void pack_w_head(const float* __restrict__ Wk, const float* __restrict__ bk,
                            const float* __restrict__ Wr, const float* __restrict__ br,
                            __bf16* __restrict__ Bh, float* __restrict__ ch){
    int gid = blockIdx.x*256 + threadIdx.x;    // 64*16 = 1024
    int k8  = gid >> 4;
    int colh = gid & 15;
    bf16x8 out;
    #pragma unroll
    for (int j=0;j<8;++j){
        int k = k8*8 + j;
        float v = 0.f;
        if (colh < 6) v = (k < HDIM) ? Wr[k*GDIM + colh] : Wk[(k-HDIM)*GDIM + colh];
        out[j] = (__bf16)v;
    }
    *(bf16x8*)(Bh + (size_t)gid*8) = out;
    if (k8 == 0)
        ch[colh] = (colh < 6) ? (Wk[FDIM*GDIM + colh] + bk[colh] + Wr[HDIM*GDIM + colh] + br[colh]) : 0.f;
}

// ---------------- persistent recurrence kernel ----------------
// 192 blocks x 320 threads. block = (rowgroup rg: 32 rows) x (colgroup cgp: 16 units)
// waves 0-3: gate `wave` for its 16 units, full K in registers; wave 4: head (6 cols).
// Cross-block data (h ping-pong, flags) uses RELAXED AGENT atomics only (L3-coherent,
// no L2 cache-walk fences). Staging is BATCHED: 256 threads x 8 chunks fully unrolled
// (all loads in flight before any use) so the ~900cy L2-bypass latency is paid once.
__global__ void __launch_bounds__(NTHR, 1) persist(
    const __bf16* __restrict__ xb, const __bf16* __restrict__ Bg, const __bf16* __restrict__ Bh,
    const float* __restrict__ cg, const float* __restrict__ ch,
    __bf16* __restrict__ hbA, __bf16* __restrict__ hbB,
    float* __restrict__ bufh, float* __restrict__ bufd,
    unsigned* __restrict__ flags)
{
    __shared__ __bf16 Alds[32*512];        // 32 KB, XOR-swizzled rows
    __shared__ float  accG[4][32][17];     // gate pre-acts (+bias), padded stride
    __shared__ float  headL[32][8];        // raw head pre-acts (+bias)

    const int tid  = threadIdx.x;
    const int wave = tid >> 6, lane = tid & 63;
    const int rg   = blockIdx.x / NCG, cgp = blockIdx.x % NCG;
    const int row0 = rg * 32;
    const int ccol = lane & 15, krow = lane >> 4;
    unsigned* myflags = flags + rg*32;     // 24 used, padded to 32

    // ---- load weights into registers (persist across all 256 steps) ----
    bf16x8 wfrag[16];
    float biasv;
    if (wave < 4){
        int colb = cgp*64 + wave*16;
        #pragma unroll
        for (int ks=0; ks<16; ++ks)
            wfrag[ks] = *(const bf16x8*)(Bg + (((size_t)ks*4 + krow)*NGC + colb + ccol)*8);
        biasv = cg[colb + ccol];
    } else {
        #pragma unroll
        for (int ks=0; ks<16; ++ks)
            wfrag[ks] = *(const bf16x8*)(Bh + (((size_t)ks*4 + krow)*16 + ccol)*8);
        biasv = ch[ccol];
    }

    // staging assignment: thread (tid<256) owns row sr, 8 consecutive 16B chunks
    const int sr  = tid >> 3;              // 0..31
    const int sk0 = (tid & 7) << 3;        // 0,8,...,56
    const int sgrow = row0 + sr;

    float creg0 = 0.f, creg1 = 0.f;        // register-resident cell state (2 rows/thread)
    unsigned ep = 0;

    for (int t=0; t<T_STEPS; ++t){
        const __bf16* hbp = (t & 1) ? hbB : hbA;
        __bf16*       hbn = (t & 1) ? hbA : hbB;

        // ---- batched stage A = [h | x_t] rows row0..row0+31 into LDS (swizzled) ----
        if (tid < 256){
            bf16x8 st[8];
            #pragma unroll
            for (int j=0;j<8;++j){
                int kk = sk0 + j;
                if (kk < 48){
                    unsigned long long* hp8 = (unsigned long long*)(hbp + (size_t)sgrow*HDIM + kk*8);
                    ulonglong2 uu;
                    uu.x = __hip_atomic_load(hp8,   __ATOMIC_RELAXED, __HIP_MEMORY_SCOPE_AGENT);
                    uu.y = __hip_atomic_load(hp8+1, __ATOMIC_RELAXED, __HIP_MEMORY_SCOPE_AGENT);
                    st[j] = __builtin_bit_cast(bf16x8, uu);
                } else {
                    st[j] = *(const bf16x8*)(xb + ((size_t)t*BATCH + sgrow)*FDIM + (kk-48)*8);
                }
            }
            #pragma unroll
            for (int j=0;j<8;++j){
                int kk = sk0 + j;
                int ei = (sr*512 + kk*8) ^ ((sr & 7) << 3);
                *(bf16x8*)(Alds + ei) = st[j];
            }
        }
        __syncthreads();

        // ---- MFMA: 2 M-tiles x 16 k-steps, B from registers ----
        f32x4 acc0 = {}, acc1 = {};
        #pragma unroll
        for (int ks=0; ks<16; ++ks){
            int kbase = ks*32 + krow*8;
            int e0 = ( ccol      *512 + kbase) ^ ((ccol & 7) << 3);
            int e1 = ((ccol + 16)*512 + kbase) ^ ((ccol & 7) << 3);
            bf16x8 a0 = *(const bf16x8*)(Alds + e0);
            bf16x8 a1 = *(const bf16x8*)(Alds + e1);
            acc0 = __builtin_amdgcn_mfma_f32_16x16x32_bf16(a0, wfrag[ks], acc0, 0,0,0);
            acc1 = __builtin_amdgcn_mfma_f32_16x16x32_bf16(a1, wfrag[ks], acc1, 0,0,0);
        }

        // ---- scatter pre-activations to LDS (C/D: col=lane&15, row=krow*4+i) ----
        if (wave < 4){
            #pragma unroll
            for (int i=0;i<4;++i){
                accG[wave][krow*4+i     ][ccol] = acc0[i] + biasv;
                accG[wave][krow*4+i + 16][ccol] = acc1[i] + biasv;
            }
        } else if (ccol < 6){
            #pragma unroll
            for (int i=0;i<4;++i){
                headL[krow*4+i     ][ccol] = acc0[i] + biasv;
                headL[krow*4+i + 16][ccol] = acc1[i] + biasv;
            }
        }
        __syncthreads();

        // ---- gates + state update: 256 threads x 2 rows, c in registers ----
        if (tid < 256){
            int ul = tid & 15;
            int rb = (tid >> 4) * 2;
            int slot = t - (T_STEPS - KWIN);
            #pragma unroll
            for (int j=0; j<2; ++j){
                int r = rb + j;
                int grow = row0 + r;
                float a0 = headL[r][0], a1 = headL[r][1], a2 = headL[r][2];
                float b0 = headL[r][3], b1 = headL[r][4], b2 = headL[r][5];
                float m1v = fmaxf(fmaxf(a0,a1),a2);
                float e0=__expf(a0-m1v), e1=__expf(a1-m1v), e2=__expf(a2-m1v);
                float inv = 1.f/(e0+e1+e2);
                float fm0 = e0*inv, fm1 = fm0 + e1*inv, fm2 = fm1 + e2*inv;
                float m2v = fmaxf(fmaxf(b0,b1),b2);
                float f0=__expf(b0-m2v), f1=__expf(b1-m2v), f2=__expf(b2-m2v);
                float inv2 = 1.f/(f0+f1+f2);
                float im2 = f2*inv2, im1 = im2 + f1*inv2, im0 = im1 + f0*inv2;
                int u = cgp*16 + ul;
                int l = u >> 7;
                float fml = (l==0)?fm0:((l==1)?fm1:fm2);
                float iml = (l==0)?im0:((l==1)?im1:im2);
                float fg = sigmoidf_(accG[0][r][ul]);
                float ig = sigmoidf_(accG[1][r][ul]);
                float og = sigmoidf_(accG[2][r][ul]);
                float ci = tanhf_  (accG[3][r][ul]);
                float cold = j ? creg1 : creg0;
                float ov = fml*iml;
                float cn = ov*(fg*cold + ig*ci) + (fml-ov)*cold + (iml-ov)*ci;
                float h  = og * tanhf_(cn);
                if (j) creg1 = cn; else creg0 = cn;
                size_t idx = (size_t)grow*HDIM + u;

                // coherent h store: pair adjacent columns (even lane stores 4B)
                unsigned short hu = __builtin_bit_cast(unsigned short, (__bf16)h);
                unsigned short hp = (unsigned short)__shfl_xor((int)hu, 1);
                if ((ul & 1) == 0){
                    unsigned hv = (unsigned)hu | ((unsigned)hp << 16);
                    __hip_atomic_store((unsigned*)(hbn + (size_t)grow*HDIM + (u & ~1)),
                                       hv, __ATOMIC_RELAXED, __HIP_MEMORY_SCOPE_AGENT);
                }
                if (slot >= 0) bufh[(size_t)slot*BH + idx] = h;    // read post-kernel only
                if (slot >= 0 && cgp == 0 && ul == 0)
                    bufd[slot*BATCH + grow] = 1.f - (fm0+fm1+fm2)*(1.f/3.f);
            }
        }

        // ---- per-rowgroup fence-free barrier (24 blocks) ----
        ++ep;
        __syncthreads();   // each wave drains vmcnt(0) -> all h-stores L3-acked
        if (tid == 0)
            __hip_atomic_store(&myflags[cgp], ep, __ATOMIC_RELAXED, __HIP_MEMORY_SCOPE_AGENT);
        if (wave == 0 && lane < NCG){
            while (__hip_atomic_load(&myflags[lane], __ATOMIC_RELAXED, __HIP_MEMORY_SCOPE_AGENT) < ep)
                ;  // tight poll: load latency is the natural pacing
        }
        __syncthreads();
    }
}

// ---------------- finals ----------------
__global__ void final_locdis(const float* __restrict__ bufd, float* __restrict__ locdis){
    int b = threadIdx.x;   // 256
    float d[KWIN]; float cum = 0.f;
    #pragma unroll
    for (int k=0;k<KWIN;++k){ cum += bufd[k*BATCH + b]; d[k] = cum; }
    float m = d[0];
    #pragma unroll
    for (int k=1;k<KWIN;++k) m = fmaxf(m, d[k]);
    float s = 0.f;
    #pragma unroll
    for (int k=0;k<KWIN;++k){ d[k] = __expf(d[k]-m); s += d[k]; }
    float invs = 1.f/s;
    #pragma unroll
    for (int k=0;k<KWIN;++k) locdis[b*KWIN + k] = d[k]*invs;
}

__global__ void final_lh(const float* __restrict__ bufh, const float* __restrict__ locdis,
                         float* __restrict__ lh, float* __restrict__ mh){
    int gid = blockIdx.x*256 + threadIdx.x;    // BH
    int b = gid / HDIM;
    int i = gid - b*HDIM;
    float s = 0.f;
    #pragma unroll
    for (int k=0;k<KWIN;++k){
        float v = bufh[(size_t)k*BH + gid] * locdis[b*KWIN + k];
        lh[(size_t)b*(HDIM*KWIN) + i*KWIN + k] = v;
        s += v;
    }
    mh[gid] = s * (1.f/KWIN);
}

__global__ __launch_bounds__(256) void final_conv(const float* __restrict__ lh, const float* __restrict__ Wc,
                                                  const float* __restrict__ bc, float* __restrict__ cvout){
    __shared__ float As[32*257];
    __shared__ float Bs[32*257];
    int tid = threadIdx.x;
    int bb = blockIdx.x / 12, ob = blockIdx.x % 12;   // 8 x 12 = 96 blocks
    int tx = tid & 15, ty = tid >> 4;
    float acc00=0.f, acc01=0.f, acc10=0.f, acc11=0.f;
    const int KD = HDIM*KWIN;   // 3840 = 15 * 256
    for (int ch=0; ch<15; ++ch){
        #pragma unroll
        for (int p=0;p<8;++p){
            int q   = tid + p*256;
            int row = q >> 6;
            int c4  = q & 63;
            float4 va = *(const float4*)(lh + (size_t)(bb*32+row)*KD + ch*256 + c4*4);
            float4 vb = *(const float4*)(Wc + (size_t)(ob*32+row)*KD + ch*256 + c4*4);
            int o = row*257 + c4*4;
            As[o+0]=va.x; As[o+1]=va.y; As[o+2]=va.z; As[o+3]=va.w;
            Bs[o+0]=vb.x; Bs[o+1]=vb.y; Bs[o+2]=vb.z; Bs[o+3]=vb.w;
        }
        __syncthreads();
        for (int kk=0; kk<256; ++kk){
            float x0 = As[ty*257+kk],      x1 = As[(ty+16)*257+kk];
            float w0 = Bs[tx*257+kk],      w1 = Bs[(tx+16)*257+kk];
            acc00 += x0*w0; acc01 += x0*w1; acc10 += x1*w0; acc11 += x1*w1;
        }
        __syncthreads();
    }
    int r0 = bb*32+ty, r1 = r0+16, o0 = ob*32+tx, o1 = o0+16;
    cvout[(size_t)r0*HDIM + o0] = acc00 + bc[o0];
    cvout[(size_t)r0*HDIM + o1] = acc01 + bc[o1];
    cvout[(size_t)r1*HDIM + o0] = acc10 + bc[o0];
    cvout[(size_t)r1*HDIM + o1] = acc11 + bc[o1];
}

__global__ void final_th1(const float* __restrict__ mh, const float* __restrict__ Ws,
                          const float* __restrict__ bs, float* __restrict__ th1){
    int gid = blockIdx.x*256 + threadIdx.x;   // 256*64
    int b = gid >> 6, s = gid & 63;
    float acc = bs[s];
    const float* mr = mh + (size_t)b*HDIM;
    for (int i=0;i<HDIM;++i) acc += mr[i] * Ws[i*SDIM + s];
    th1[gid] = fmaxf(acc, 0.f);
}

__global__ void final_theme(const float* __restrict__ th1, const float* __restrict__ Wrs,
                            const float* __restrict__ brs, float* __restrict__ theme){
    int gid = blockIdx.x*256 + threadIdx.x;   // BH
    int b = gid / HDIM, o = gid - b*HDIM;
    float acc = brs[o];
    const float* tr = th1 + b*SDIM;
    for (int j=0;j<SDIM;++j) acc += tr[j] * Wrs[j*HDIM + o];
    theme[gid] = sigmoidf_(acc);
}

__global__ void final_out(const float* __restrict__ theme, const float* __restrict__ cvout,
                          const float* __restrict__ bufh, const float* __restrict__ Wo,
                          const float* __restrict__ bo, float* __restrict__ out){
    int b = blockIdx.x, lane = threadIdx.x;   // 256 blocks x 64 threads
    const float* hlast = bufh + (size_t)(KWIN-1)*BH;   // h at t=T-1
    float s = 0.f;
    for (int u=lane; u<HDIM; u+=64){
        float r = theme[(size_t)b*HDIM+u]*cvout[(size_t)b*HDIM+u] + hlast[(size_t)b*HDIM+u];
        s += r * Wo[u];
    }
    #pragma unroll
    for (int off=32; off; off>>=1) s += __shfl_down(s, off);
    if (lane == 0) out[b] = sigmoidf_(s + bo[0]);
}

extern "C" void kernel_launch(void* const* d_in, const int* in_sizes, int n_in,
                              void* d_out, int out_size, void* d_ws, size_t ws_size,
                              hipStream_t stream){
    const float* x   = (const float*)d_in[0];
    const float* Wk  = (const float*)d_in[1];
    const float* bk  = (const float*)d_in[2];
    const float* Wr  = (const float*)d_in[3];
    const float* br  = (const float*)d_in[4];
    const float* Ws  = (const float*)d_in[5];
    const float* bs  = (const float*)d_in[6];
    const float* Wrs = (const float*)d_in[7];
    const float* brs = (const float*)d_in[8];
    const float* Wc  = (const float*)d_in[9];
    const float* bc  = (const float*)d_in[10];
    const float* Wo  = (const float*)d_in[11];
    const float* bo  = (const float*)d_in[12];
    float* out = (float*)d_out;

    char* w = (char*)d_ws;
    auto alloc = [&](size_t bytes)->char*{ char* p = w; w += (bytes + 255) & ~(size_t)255; return p; };
    __bf16* xb    = (__bf16*)alloc((size_t)T_STEPS*BATCH*FDIM*2);   // 16.8 MB
    __bf16* Bg    = (__bf16*)alloc((size_t)(KA/8)*NGC*8*2);         // 1.57 MB
    __bf16* Bh    = (__bf16*)alloc((size_t)(KA/8)*16*8*2);          // 16 KB
    float* cg     = (float*) alloc(NGC*4);
    float* ch     = (float*) alloc(16*4);
    __bf16* hbA   = (__bf16*)alloc((size_t)BH*2);
    __bf16* hbB   = (__bf16*)alloc((size_t)BH*2);
    float* bufh   = (float*) alloc((size_t)KWIN*BH*4);
    float* bufd   = (float*) alloc((size_t)KWIN*BATCH*4);
    float* locdis = (float*) alloc((size_t)BATCH*KWIN*4);
    float* lh     = (float*) alloc((size_t)BATCH*HDIM*KWIN*4);
    float* mh     = (float*) alloc((size_t)BH*4);
    float* th1    = (float*) alloc((size_t)BATCH*SDIM*4);
    float* theme  = (float*) alloc((size_t)BH*4);
    float* convb  = (float*) alloc((size_t)BH*4);
    unsigned* flags = (unsigned*)alloc(NRG*32*4);

    init_state<<<dim3(BH/256), dim3(256), 0, stream>>>(hbA, flags);
    cast_x<<<dim3((T_STEPS*BATCH*FDIM)/4/256), dim3(256), 0, stream>>>(x, xb, T_STEPS*BATCH*FDIM);
    pack_w_gate<<<dim3((KA/8)*NGC/256), dim3(256), 0, stream>>>(Wk, bk, Wr, br, Bg, cg);
    pack_w_head<<<dim3((KA/8)*16/256), dim3(256), 0, stream>>>(Wk, bk, Wr, br, Bh, ch);

    {
        void* args[] = { (void*)&xb, (void*)&Bg, (void*)&Bh, (void*)&cg, (void*)&ch,
                         (void*)&hbA, (void*)&hbB, (void*)&bufh, (void*)&bufd,
                         (void*)&flags };
        hipLaunchCooperativeKernel((void*)persist, dim3(NBLK), dim3(NTHR), args, 0, stream);
    }

    final_locdis<<<dim3(1),   dim3(256), 0, stream>>>(bufd, locdis);
    final_lh    <<<dim3(BH/256), dim3(256), 0, stream>>>(bufh, locdis, lh, mh);
    final_conv  <<<dim3(96),  dim3(256), 0, stream>>>(lh, Wc, bc, convb);
    final_th1   <<<dim3(BATCH*SDIM/256), dim3(256), 0, stream>>>(mh, Ws, bs, th1);
    final_theme <<<dim3(BH/256), dim3(256), 0, stream>>>(th1, Wrs, brs, theme);
    final_out   <<<dim3(BATCH), dim3(64), 0, stream>>>(theme, convb, bufh, Wo, bo, out);
}